// Round 2
// baseline (887.648 us; speedup 1.0000x reference)
//
#include <hip/hip_runtime.h>
#include <hip/hip_bf16.h>
#include <math.h>

// AdaptiveContrastiveLoss: x[4096][512] f32 -> scalar f32.
// R1: bf16-MFMA GEMM for sim = Xn*Xn^T, uniform-value binning (8192 bins)
// + single compact/loss pass + exact in-key-space select on ~15k candidates.
// ws layout: sim 64MB | xnb 4MB | posCand 1MB | negCand 1MB | Meta (~33KB).

#define N 4096
#define D 512
#define NN 16777216u
#define NB 8192          // uniform value bins
#define CAND_CAP 262144  // per-side candidate capacity (1MB)

typedef __attribute__((ext_vector_type(8))) short bf16x8;
typedef __attribute__((ext_vector_type(4))) float f32x4;

struct Meta {
  unsigned int hist[NB];
  unsigned int bp, rwp;      // pos threshold bin + rank within bin
  unsigned int bn_, rwn;     // neg threshold bin + rank within bin
  unsigned int pcCnt, ncCnt; // candidate counts
  unsigned int pcnt, ncnt;   // strict mask counts (accumulated)
  double psum, nsum;         // strict mask numerators
};

// monotone value->bin (identical instruction in every kernel: single fmaf)
__device__ __forceinline__ int val2bin(float s) {
  int b = (int)fmaf(s, 4096.0f, 4096.0f);  // floor((s+1)*4096) for s>=-1
  return b < 0 ? 0 : (b > NB - 1 ? NB - 1 : b);
}
// monotone float<->sortable-uint (no NaNs in this data)
__device__ __forceinline__ unsigned int f2key(float f) {
  unsigned int u = __float_as_uint(f);
  return (u & 0x80000000u) ? ~u : (u | 0x80000000u);
}
__device__ __forceinline__ float key2f(unsigned int k) {
  unsigned int u = (k & 0x80000000u) ? (k ^ 0x80000000u) : ~k;
  return __uint_as_float(u);
}
__device__ __forceinline__ unsigned short f2bf(float f) {  // RNE, matches __float2bfloat16
  unsigned int u = __float_as_uint(f);
  u += 0x7FFFu + ((u >> 16) & 1u);
  return (unsigned short)(u >> 16);
}

// ---- 1) row norms + normalize + f32->bf16 convert. one block per row ----
__global__ __launch_bounds__(256) void norm_conv(const float* __restrict__ x,
                                                 unsigned short* __restrict__ xnb) {
  const int row = blockIdx.x;
  const int tid = threadIdx.x;  // 256 threads x 2 floats
  const float2 v = ((const float2*)(x + (size_t)row * D))[tid];
  float s = v.x * v.x + v.y * v.y;
#pragma unroll
  for (int o = 32; o > 0; o >>= 1) s += __shfl_xor(s, o);
  __shared__ float wsum[4];
  __shared__ float s_rinv;
  if ((tid & 63) == 0) wsum[tid >> 6] = s;
  __syncthreads();
  if (tid == 0) {
    float t = wsum[0] + wsum[1] + wsum[2] + wsum[3];
    s_rinv = 1.0f / fmaxf(sqrtf(t), 1e-8f);
  }
  __syncthreads();
  const float r = s_rinv;
  unsigned short lo = f2bf(v.x * r), hi = f2bf(v.y * r);
  ((ushort2*)(xnb + (size_t)row * D))[tid] = make_ushort2(lo, hi);
}

// ---- 2) bf16 MFMA GEMM: sim = Xnb * Xnb^T, 128x128 tile, 4 waves ----
#define BM 128
#define BK 64
#define LDK 72  // padded row stride (144B = 16*9: 16B-aligned, 2-way-bank free)
__global__ __launch_bounds__(256) void gemm_sim(const unsigned short* __restrict__ xnb,
                                                float* __restrict__ sim) {
  __shared__ unsigned short As[BM][LDK];
  __shared__ unsigned short Bs[BM][LDK];
  const int tid = threadIdx.x;
  const int bm = blockIdx.x * BM;
  const int bn = blockIdx.y * BM;
  const int w = tid >> 6, l = tid & 63;
  const int wr = w >> 1, wc = w & 1;
  const int lr = l & 15, lk = (l >> 4) * 8;

  const int srow = tid >> 3;        // 0..31
  const int skoff = (tid & 7) * 8;  // 0..56

  f32x4 acc[4][4] = {};

  for (int kt = 0; kt < D; kt += BK) {
    bf16x8 av[4], bv[4];
#pragma unroll
    for (int r4 = 0; r4 < 4; ++r4) {
      const int row = srow + r4 * 32;
      av[r4] = *(const bf16x8*)&xnb[(size_t)(bm + row) * D + kt + skoff];
      bv[r4] = *(const bf16x8*)&xnb[(size_t)(bn + row) * D + kt + skoff];
    }
    __syncthreads();  // previous tile's compute done
#pragma unroll
    for (int r4 = 0; r4 < 4; ++r4) {
      const int row = srow + r4 * 32;
      *(bf16x8*)&As[row][skoff] = av[r4];
      *(bf16x8*)&Bs[row][skoff] = bv[r4];
    }
    __syncthreads();
#pragma unroll
    for (int kk = 0; kk < BK; kk += 32) {
      bf16x8 af[4], bf[4];
#pragma unroll
      for (int m = 0; m < 4; ++m)
        af[m] = *(const bf16x8*)&As[wr * 64 + m * 16 + lr][kk + lk];
#pragma unroll
      for (int n = 0; n < 4; ++n)
        bf[n] = *(const bf16x8*)&Bs[wc * 64 + n * 16 + lr][kk + lk];
#pragma unroll
      for (int m = 0; m < 4; ++m)
#pragma unroll
        for (int n = 0; n < 4; ++n)
          acc[m][n] = __builtin_amdgcn_mfma_f32_16x16x32_bf16(af[m], bf[n], acc[m][n], 0, 0, 0);
    }
  }
  // C/D layout: col = lane&15, row = (lane>>4)*4 + e  [measured m89/m91]
  const int orow = bm + wr * 64 + (l >> 4) * 4;
  const int ocol = bn + wc * 64 + lr;
#pragma unroll
  for (int m = 0; m < 4; ++m)
#pragma unroll
    for (int n = 0; n < 4; ++n)
#pragma unroll
      for (int e = 0; e < 4; ++e)
        sim[(size_t)(orow + m * 16 + e) * N + ocol + n * 16] = acc[m][n][e];
}

// ---- 3) uniform 8192-bin histogram of all sim values ----
__global__ __launch_bounds__(256) void hist_pass(const float* __restrict__ sim,
                                                 Meta* __restrict__ m) {
  __shared__ unsigned int h[NB];
  const int tid = threadIdx.x;
  for (int i = tid; i < NB; i += 256) h[i] = 0;
  __syncthreads();
  const size_t stride = (size_t)gridDim.x * blockDim.x;
  for (size_t i = (size_t)blockIdx.x * blockDim.x + tid; i < NN / 4; i += stride) {
    const float4 v = ((const float4*)sim)[i];
    atomicAdd(&h[val2bin(v.x)], 1u);
    atomicAdd(&h[val2bin(v.y)], 1u);
    atomicAdd(&h[val2bin(v.z)], 1u);
    atomicAdd(&h[val2bin(v.w)], 1u);
  }
  __syncthreads();
  for (int i = tid; i < NB; i += 256) {
    const unsigned int v = h[i];
    if (v) atomicAdd(&m->hist[i], v);
  }
}

// ---- 4) find the two threshold bins + ranks within ----
__global__ __launch_bounds__(256) void scan_bins(Meta* __restrict__ m,
                                                 unsigned int kneg, unsigned int kpos) {
  __shared__ unsigned int part[256];
  const int tid = threadIdx.x;
  unsigned int s = 0;
  for (int i = 0; i < NB / 256; ++i) s += m->hist[tid * (NB / 256) + i];
  part[tid] = s;
  __syncthreads();
  if (tid == 0) {
    const unsigned int targets[2] = {kpos, kneg};
    unsigned int outb[2], outr[2];
    for (int t = 0; t < 2; ++t) {
      unsigned int r = targets[t], cum = 0, seg = 0;
      while (seg < 255 && cum + part[seg] <= r) { cum += part[seg]; seg++; }
      unsigned int b = seg * (NB / 256);
      while (b < NB - 1 && cum + m->hist[b] <= r) { cum += m->hist[b]; b++; }
      outb[t] = b;
      outr[t] = r - cum;
    }
    m->bp = outb[0]; m->rwp = outr[0];
    m->bn_ = outb[1]; m->rwn = outr[1];
  }
}

__device__ __forceinline__ void wave_append(float s, bool pred,
                                            float* __restrict__ buf,
                                            unsigned int* __restrict__ ctr) {
  const unsigned long long mask = __ballot(pred);
  if (!mask) return;
  const int lane = threadIdx.x & 63;
  const int leader = __ffsll((unsigned long long)mask) - 1;
  unsigned int base = 0;
  if (lane == leader) base = atomicAdd(ctr, (unsigned int)__popcll(mask));
  base = __shfl(base, leader, 64);
  if (pred) {
    const unsigned int idx = base + __popcll(mask & ((1ull << lane) - 1ull));
    if (idx < CAND_CAP) buf[idx] = s;
  }
}

// ---- 5) fused: aggregate non-boundary bins' loss parts + compact boundary bins ----
__global__ __launch_bounds__(256) void compact_loss(const float* __restrict__ sim,
                                                    Meta* __restrict__ m,
                                                    float* __restrict__ pcand,
                                                    float* __restrict__ ncand) {
  const int tid = threadIdx.x;
  const unsigned int bp = m->bp, bn = m->bn_;
  float ps = 0.f, ns = 0.f;
  unsigned int pc = 0, nc = 0;
  const size_t stride = (size_t)gridDim.x * blockDim.x;
  for (size_t i = (size_t)blockIdx.x * blockDim.x + tid; i < NN / 4; i += stride) {
    const float4 v = ((const float4*)sim)[i];
    const float f[4] = {v.x, v.y, v.z, v.w};
#pragma unroll
    for (int e = 0; e < 4; ++e) {
      const float s = f[e];
      const unsigned int b = (unsigned int)val2bin(s);
      if (b > bp) { pc++; ps += fmaxf(1.0f - s, 0.0f); }
      if (b < bn) { nc++; ns += fmaxf(s, 0.0f); }
      wave_append(s, b == bp, pcand, &m->pcCnt);
      wave_append(s, b == bn, ncand, &m->ncCnt);
    }
  }
  double psd = ps, nsd = ns;
#pragma unroll
  for (int o = 32; o > 0; o >>= 1) {
    psd += __shfl_xor(psd, o);
    nsd += __shfl_xor(nsd, o);
    pc += __shfl_xor(pc, o);
    nc += __shfl_xor(nc, o);
  }
  __shared__ double sps[4], sns[4];
  __shared__ unsigned int spc[4], snc[4];
  if ((tid & 63) == 0) { const int w = tid >> 6; sps[w] = psd; sns[w] = nsd; spc[w] = pc; snc[w] = nc; }
  __syncthreads();
  if (tid == 0) {
    atomicAdd(&m->psum, sps[0] + sps[1] + sps[2] + sps[3]);
    atomicAdd(&m->nsum, sns[0] + sns[1] + sns[2] + sns[3]);
    atomicAdd(&m->pcnt, spc[0] + spc[1] + spc[2] + spc[3]);
    atomicAdd(&m->ncnt, snc[0] + snc[1] + snc[2] + snc[3]);
  }
}

// ---- 6) exact select on candidates (key-space narrowing) + finalize ----
__global__ __launch_bounds__(256) void select_finalize(Meta* __restrict__ m,
                                                       const float* __restrict__ pcand,
                                                       const float* __restrict__ ncand,
                                                       float* __restrict__ out) {
  __shared__ unsigned int h[1024];
  __shared__ unsigned int s_lo, s_hi, s_r;
  __shared__ unsigned int rmin[4], rmax[4], rcnt[4];
  __shared__ double racc[4];
  const int tid = threadIdx.x;
  const int lane = tid & 63, wid = tid >> 6;

  for (int side = 0; side < 2; ++side) {
    const unsigned int rawCnt = side ? m->ncCnt : m->pcCnt;
    const unsigned int cnt = rawCnt < CAND_CAP ? rawCnt : CAND_CAP;
    const float* cand = side ? ncand : pcand;
    if (tid == 0) s_r = side ? m->rwn : m->rwp;

    // key min/max over candidates
    unsigned int kmin = 0xFFFFFFFFu, kmax = 0u;
    for (unsigned int i = tid; i < cnt; i += 256) {
      const unsigned int k = f2key(cand[i]);
      kmin = min(kmin, k); kmax = max(kmax, k);
    }
#pragma unroll
    for (int o = 32; o > 0; o >>= 1) {
      kmin = min(kmin, (unsigned int)__shfl_xor((int)kmin, o));
      kmax = max(kmax, (unsigned int)__shfl_xor((int)kmax, o));
    }
    if (lane == 0) { rmin[wid] = kmin; rmax[wid] = kmax; }
    __syncthreads();
    if (tid == 0) {
      s_lo = min(min(rmin[0], rmin[1]), min(rmin[2], rmin[3]));
      s_hi = max(max(rmax[0], rmax[1]), max(rmax[2], rmax[3])) + 1u;
    }

    // narrow [lo,hi) by 1024-way histogram until single key
    for (;;) {
      __syncthreads();
      const unsigned int lo = s_lo, hi = s_hi;
      if (hi - lo <= 1u) break;
      const unsigned int span = hi - lo;
      unsigned int shift = 0;
      while (((span - 1u) >> shift) > 1023u) shift++;
      for (int i = tid; i < 1024; i += 256) h[i] = 0;
      __syncthreads();
      for (unsigned int i = tid; i < cnt; i += 256) {
        const unsigned int k = f2key(cand[i]);
        if (k >= lo && k < hi) atomicAdd(&h[(k - lo) >> shift], 1u);
      }
      __syncthreads();
      if (tid == 0) {
        unsigned int r = s_r, cum = 0, d = 0;
        for (; d < 1024; ++d) { const unsigned int c = h[d]; if (cum + c > r) break; cum += c; }
        if (d == 1024) d = 1023;
        s_r = r - cum;
        const unsigned int nlo = lo + (d << shift);
        unsigned int nhi = nlo + (1u << shift);
        if (nhi > hi || nhi < nlo) nhi = hi;
        s_lo = nlo; s_hi = nhi;
      }
    }
    __syncthreads();
    const float T = key2f(s_lo);

    // strict boundary contributions
    float accf = 0.f;
    unsigned int c2 = 0;
    for (unsigned int i = tid; i < cnt; i += 256) {
      const float s = cand[i];
      if (side == 0) { if (s > T) { c2++; accf += fmaxf(1.0f - s, 0.0f); } }
      else           { if (s < T) { c2++; accf += fmaxf(s, 0.0f); } }
    }
    double accd = accf;
#pragma unroll
    for (int o = 32; o > 0; o >>= 1) { accd += __shfl_xor(accd, o); c2 += __shfl_xor(c2, o); }
    if (lane == 0) { racc[wid] = accd; rcnt[wid] = c2; }
    __syncthreads();
    if (tid == 0) {
      const double a = racc[0] + racc[1] + racc[2] + racc[3];
      const unsigned int c = rcnt[0] + rcnt[1] + rcnt[2] + rcnt[3];
      if (side == 0) { m->psum += a; m->pcnt += c; }
      else           { m->nsum += a; m->ncnt += c; }
    }
    __syncthreads();
  }
  if (tid == 0)
    out[0] = (float)(m->psum / (double)m->pcnt + m->nsum / (double)m->ncnt);
}

extern "C" void kernel_launch(void* const* d_in, const int* in_sizes, int n_in,
                              void* d_out, int out_size, void* d_ws, size_t ws_size,
                              hipStream_t stream) {
  const float* x = (const float*)d_in[0];
  float* out = (float*)d_out;
  char* ws = (char*)d_ws;

  float* sim = (float*)ws;                                        // 64 MB
  unsigned short* xnb = (unsigned short*)(ws + (size_t)NN * 4);   // 4 MB
  float* pcand = (float*)(ws + (size_t)NN * 4 + (size_t)N * D * 2);          // 1 MB
  float* ncand = (float*)(ws + (size_t)NN * 4 + (size_t)N * D * 2 + CAND_CAP * 4);
  Meta* meta = (Meta*)(ws + (size_t)NN * 4 + (size_t)N * D * 2 + 2 * CAND_CAP * 4);

  const unsigned int kneg = (unsigned int)ceil((double)NN * 0.2);          // 3355444
  const unsigned int kpos = (unsigned int)ceil((double)NN * (1.0 - 0.2));  // 13421773

  hipMemsetAsync(meta, 0, sizeof(Meta), stream);
  norm_conv<<<N, 256, 0, stream>>>(x, xnb);
  dim3 ggrid(N / BM, N / BM);
  gemm_sim<<<ggrid, 256, 0, stream>>>(xnb, sim);
  hist_pass<<<1024, 256, 0, stream>>>(sim, meta);
  scan_bins<<<1, 256, 0, stream>>>(meta, kneg, kpos);
  compact_loss<<<1024, 256, 0, stream>>>(sim, meta, pcand, ncand);
  select_finalize<<<1, 256, 0, stream>>>(meta, pcand, ncand, out);
}

// Round 3
// 342.245 us; speedup vs baseline: 2.5936x; 2.5936x over previous
//
#include <hip/hip_runtime.h>
#include <hip/hip_bf16.h>
#include <math.h>

// AdaptiveContrastiveLoss: x[4096][512] f32 -> scalar f32.
// R2: replaced per-element ballot/global-atomic candidate append (615us stall,
// VALUBusy 1.5%) with per-block LDS candidate buffers + one flush per block.
// select_finalize widened to 1024 threads.
// ws layout: sim 64MB | xnb 4MB | posCand 1MB | negCand 1MB | Meta (~33KB).

#define N 4096
#define D 512
#define NN 16777216u
#define NB 8192          // uniform value bins
#define CAND_CAP 262144  // per-side global candidate capacity (1MB)
#define LCAP 2048        // per-block LDS candidate capacity (expected ~51/block)

typedef __attribute__((ext_vector_type(8))) short bf16x8;
typedef __attribute__((ext_vector_type(4))) float f32x4;

struct Meta {
  unsigned int hist[NB];
  unsigned int bp, rwp;      // pos threshold bin + rank within bin
  unsigned int bn_, rwn;     // neg threshold bin + rank within bin
  unsigned int pcCnt, ncCnt; // candidate counts
  unsigned int pcnt, ncnt;   // strict mask counts (accumulated)
  double psum, nsum;         // strict mask numerators
};

// monotone value->bin (identical instruction in every kernel: single fmaf)
__device__ __forceinline__ int val2bin(float s) {
  int b = (int)fmaf(s, 4096.0f, 4096.0f);  // floor((s+1)*4096) for s>=-1
  return b < 0 ? 0 : (b > NB - 1 ? NB - 1 : b);
}
// monotone float<->sortable-uint (no NaNs in this data)
__device__ __forceinline__ unsigned int f2key(float f) {
  unsigned int u = __float_as_uint(f);
  return (u & 0x80000000u) ? ~u : (u | 0x80000000u);
}
__device__ __forceinline__ float key2f(unsigned int k) {
  unsigned int u = (k & 0x80000000u) ? (k ^ 0x80000000u) : ~k;
  return __uint_as_float(u);
}
__device__ __forceinline__ unsigned short f2bf(float f) {  // RNE, matches __float2bfloat16
  unsigned int u = __float_as_uint(f);
  u += 0x7FFFu + ((u >> 16) & 1u);
  return (unsigned short)(u >> 16);
}

// ---- 1) row norms + normalize + f32->bf16 convert. one block per row ----
__global__ __launch_bounds__(256) void norm_conv(const float* __restrict__ x,
                                                 unsigned short* __restrict__ xnb) {
  const int row = blockIdx.x;
  const int tid = threadIdx.x;  // 256 threads x 2 floats
  const float2 v = ((const float2*)(x + (size_t)row * D))[tid];
  float s = v.x * v.x + v.y * v.y;
#pragma unroll
  for (int o = 32; o > 0; o >>= 1) s += __shfl_xor(s, o);
  __shared__ float wsum[4];
  __shared__ float s_rinv;
  if ((tid & 63) == 0) wsum[tid >> 6] = s;
  __syncthreads();
  if (tid == 0) {
    float t = wsum[0] + wsum[1] + wsum[2] + wsum[3];
    s_rinv = 1.0f / fmaxf(sqrtf(t), 1e-8f);
  }
  __syncthreads();
  const float r = s_rinv;
  unsigned short lo = f2bf(v.x * r), hi = f2bf(v.y * r);
  ((ushort2*)(xnb + (size_t)row * D))[tid] = make_ushort2(lo, hi);
}

// ---- 2) bf16 MFMA GEMM: sim = Xnb * Xnb^T, 128x128 tile, 4 waves ----
#define BM 128
#define BK 64
#define LDK 72  // padded row stride (144B = 16*9: 16B-aligned, 2-way-bank free)
__global__ __launch_bounds__(256) void gemm_sim(const unsigned short* __restrict__ xnb,
                                                float* __restrict__ sim) {
  __shared__ unsigned short As[BM][LDK];
  __shared__ unsigned short Bs[BM][LDK];
  const int tid = threadIdx.x;
  const int bm = blockIdx.x * BM;
  const int bn = blockIdx.y * BM;
  const int w = tid >> 6, l = tid & 63;
  const int wr = w >> 1, wc = w & 1;
  const int lr = l & 15, lk = (l >> 4) * 8;

  const int srow = tid >> 3;        // 0..31
  const int skoff = (tid & 7) * 8;  // 0..56

  f32x4 acc[4][4] = {};

  for (int kt = 0; kt < D; kt += BK) {
    bf16x8 av[4], bv[4];
#pragma unroll
    for (int r4 = 0; r4 < 4; ++r4) {
      const int row = srow + r4 * 32;
      av[r4] = *(const bf16x8*)&xnb[(size_t)(bm + row) * D + kt + skoff];
      bv[r4] = *(const bf16x8*)&xnb[(size_t)(bn + row) * D + kt + skoff];
    }
    __syncthreads();  // previous tile's compute done
#pragma unroll
    for (int r4 = 0; r4 < 4; ++r4) {
      const int row = srow + r4 * 32;
      *(bf16x8*)&As[row][skoff] = av[r4];
      *(bf16x8*)&Bs[row][skoff] = bv[r4];
    }
    __syncthreads();
#pragma unroll
    for (int kk = 0; kk < BK; kk += 32) {
      bf16x8 af[4], bf[4];
#pragma unroll
      for (int m = 0; m < 4; ++m)
        af[m] = *(const bf16x8*)&As[wr * 64 + m * 16 + lr][kk + lk];
#pragma unroll
      for (int n = 0; n < 4; ++n)
        bf[n] = *(const bf16x8*)&Bs[wc * 64 + n * 16 + lr][kk + lk];
#pragma unroll
      for (int m = 0; m < 4; ++m)
#pragma unroll
        for (int n = 0; n < 4; ++n)
          acc[m][n] = __builtin_amdgcn_mfma_f32_16x16x32_bf16(af[m], bf[n], acc[m][n], 0, 0, 0);
    }
  }
  // C/D layout: col = lane&15, row = (lane>>4)*4 + e  [measured m89/m91]
  const int orow = bm + wr * 64 + (l >> 4) * 4;
  const int ocol = bn + wc * 64 + lr;
#pragma unroll
  for (int m = 0; m < 4; ++m)
#pragma unroll
    for (int n = 0; n < 4; ++n)
#pragma unroll
      for (int e = 0; e < 4; ++e)
        sim[(size_t)(orow + m * 16 + e) * N + ocol + n * 16] = acc[m][n][e];
}

// ---- 3) uniform 8192-bin histogram of all sim values ----
__global__ __launch_bounds__(256) void hist_pass(const float* __restrict__ sim,
                                                 Meta* __restrict__ m) {
  __shared__ unsigned int h[NB];
  const int tid = threadIdx.x;
  for (int i = tid; i < NB; i += 256) h[i] = 0;
  __syncthreads();
  const size_t stride = (size_t)gridDim.x * blockDim.x;
  for (size_t i = (size_t)blockIdx.x * blockDim.x + tid; i < NN / 4; i += stride) {
    const float4 v = ((const float4*)sim)[i];
    atomicAdd(&h[val2bin(v.x)], 1u);
    atomicAdd(&h[val2bin(v.y)], 1u);
    atomicAdd(&h[val2bin(v.z)], 1u);
    atomicAdd(&h[val2bin(v.w)], 1u);
  }
  __syncthreads();
  for (int i = tid; i < NB; i += 256) {
    const unsigned int v = h[i];
    if (v) atomicAdd(&m->hist[i], v);
  }
}

// ---- 4) find the two threshold bins + ranks within ----
__global__ __launch_bounds__(256) void scan_bins(Meta* __restrict__ m,
                                                 unsigned int kneg, unsigned int kpos) {
  __shared__ unsigned int part[256];
  const int tid = threadIdx.x;
  unsigned int s = 0;
  for (int i = 0; i < NB / 256; ++i) s += m->hist[tid * (NB / 256) + i];
  part[tid] = s;
  __syncthreads();
  if (tid == 0) {
    const unsigned int targets[2] = {kpos, kneg};
    unsigned int outb[2], outr[2];
    for (int t = 0; t < 2; ++t) {
      unsigned int r = targets[t], cum = 0, seg = 0;
      while (seg < 255 && cum + part[seg] <= r) { cum += part[seg]; seg++; }
      unsigned int b = seg * (NB / 256);
      while (b < NB - 1 && cum + m->hist[b] <= r) { cum += m->hist[b]; b++; }
      outb[t] = b;
      outr[t] = r - cum;
    }
    m->bp = outb[0]; m->rwp = outr[0];
    m->bn_ = outb[1]; m->rwn = outr[1];
  }
}

// ---- 5) fused: strict-side loss accumulation + per-block LDS candidate compact ----
__global__ __launch_bounds__(256) void compact_loss(const float* __restrict__ sim,
                                                    Meta* __restrict__ m,
                                                    float* __restrict__ pcand,
                                                    float* __restrict__ ncand) {
  __shared__ float lp[LCAP], ln[LCAP];
  __shared__ unsigned int lpc, lnc, pbase, nbase;
  const int tid = threadIdx.x;
  if (tid == 0) { lpc = 0; lnc = 0; }
  __syncthreads();
  const unsigned int bp = m->bp, bn = m->bn_;
  float ps = 0.f, ns = 0.f;
  unsigned int pc = 0, nc = 0;
  const size_t stride = (size_t)gridDim.x * blockDim.x;
  for (size_t i = (size_t)blockIdx.x * blockDim.x + tid; i < NN / 4; i += stride) {
    const float4 v = ((const float4*)sim)[i];
    const float f[4] = {v.x, v.y, v.z, v.w};
#pragma unroll
    for (int e = 0; e < 4; ++e) {
      const float s = f[e];
      const unsigned int b = (unsigned int)val2bin(s);
      if (b > bp) { pc++; ps += fmaxf(1.0f - s, 0.0f); }
      else if (b == bp) { const unsigned int idx = atomicAdd(&lpc, 1u); if (idx < LCAP) lp[idx] = s; }
      if (b < bn) { nc++; ns += fmaxf(s, 0.0f); }
      else if (b == bn) { const unsigned int idx = atomicAdd(&lnc, 1u); if (idx < LCAP) ln[idx] = s; }
    }
  }
  double psd = ps, nsd = ns;
#pragma unroll
  for (int o = 32; o > 0; o >>= 1) {
    psd += __shfl_xor(psd, o);
    nsd += __shfl_xor(nsd, o);
    pc += __shfl_xor(pc, o);
    nc += __shfl_xor(nc, o);
  }
  __shared__ double sps[4], sns[4];
  __shared__ unsigned int spc[4], snc[4];
  if ((tid & 63) == 0) { const int w = tid >> 6; sps[w] = psd; sns[w] = nsd; spc[w] = pc; snc[w] = nc; }
  __syncthreads();
  if (tid == 0) {
    atomicAdd(&m->psum, sps[0] + sps[1] + sps[2] + sps[3]);
    atomicAdd(&m->nsum, sns[0] + sns[1] + sns[2] + sns[3]);
    atomicAdd(&m->pcnt, spc[0] + spc[1] + spc[2] + spc[3]);
    atomicAdd(&m->ncnt, snc[0] + snc[1] + snc[2] + snc[3]);
    // one global atomic per block per side
    pbase = atomicAdd(&m->pcCnt, lpc < LCAP ? lpc : LCAP);
    nbase = atomicAdd(&m->ncCnt, lnc < LCAP ? lnc : LCAP);
  }
  __syncthreads();
  const unsigned int npf = lpc < LCAP ? lpc : LCAP;
  const unsigned int nnf = lnc < LCAP ? lnc : LCAP;
  for (unsigned int i = tid; i < npf; i += 256) {
    const unsigned int gi = pbase + i;
    if (gi < CAND_CAP) pcand[gi] = lp[i];
  }
  for (unsigned int i = tid; i < nnf; i += 256) {
    const unsigned int gi = nbase + i;
    if (gi < CAND_CAP) ncand[gi] = ln[i];
  }
}

// ---- 6) exact select on candidates (key-space narrowing) + finalize ----
#define SF_T 1024
__global__ __launch_bounds__(SF_T) void select_finalize(Meta* __restrict__ m,
                                                        const float* __restrict__ pcand,
                                                        const float* __restrict__ ncand,
                                                        float* __restrict__ out) {
  __shared__ unsigned int h[1024];
  __shared__ unsigned int s_lo, s_hi, s_r;
  __shared__ unsigned int rmin[16], rmax[16], rcnt[16];
  __shared__ double racc[16];
  const int tid = threadIdx.x;
  const int lane = tid & 63, wid = tid >> 6;

  for (int side = 0; side < 2; ++side) {
    const unsigned int rawCnt = side ? m->ncCnt : m->pcCnt;
    const unsigned int cnt = rawCnt < CAND_CAP ? rawCnt : CAND_CAP;
    const float* cand = side ? ncand : pcand;
    if (tid == 0) s_r = side ? m->rwn : m->rwp;

    // key min/max over candidates
    unsigned int kmin = 0xFFFFFFFFu, kmax = 0u;
    for (unsigned int i = tid; i < cnt; i += SF_T) {
      const unsigned int k = f2key(cand[i]);
      kmin = min(kmin, k); kmax = max(kmax, k);
    }
#pragma unroll
    for (int o = 32; o > 0; o >>= 1) {
      kmin = min(kmin, (unsigned int)__shfl_xor((int)kmin, o));
      kmax = max(kmax, (unsigned int)__shfl_xor((int)kmax, o));
    }
    if (lane == 0) { rmin[wid] = kmin; rmax[wid] = kmax; }
    __syncthreads();
    if (tid == 0) {
      unsigned int lo = 0xFFFFFFFFu, hi = 0u;
      for (int i = 0; i < SF_T / 64; ++i) { lo = min(lo, rmin[i]); hi = max(hi, rmax[i]); }
      s_lo = lo; s_hi = hi + 1u;
    }

    // narrow [lo,hi) by 1024-way histogram until single key
    for (;;) {
      __syncthreads();
      const unsigned int lo = s_lo, hi = s_hi;
      if (hi - lo <= 1u) break;
      const unsigned int span = hi - lo;
      unsigned int shift = 0;
      while (((span - 1u) >> shift) > 1023u) shift++;
      for (int i = tid; i < 1024; i += SF_T) h[i] = 0;
      __syncthreads();
      for (unsigned int i = tid; i < cnt; i += SF_T) {
        const unsigned int k = f2key(cand[i]);
        if (k >= lo && k < hi) atomicAdd(&h[(k - lo) >> shift], 1u);
      }
      __syncthreads();
      if (tid == 0) {
        unsigned int r = s_r, cum = 0, d = 0;
        for (; d < 1024; ++d) { const unsigned int c = h[d]; if (cum + c > r) break; cum += c; }
        if (d == 1024) d = 1023;
        s_r = r - cum;
        const unsigned int nlo = lo + (d << shift);
        unsigned int nhi = nlo + (1u << shift);
        if (nhi > hi || nhi < nlo) nhi = hi;
        s_lo = nlo; s_hi = nhi;
      }
    }
    __syncthreads();
    const float T = key2f(s_lo);

    // strict boundary contributions
    float accf = 0.f;
    unsigned int c2 = 0;
    for (unsigned int i = tid; i < cnt; i += SF_T) {
      const float s = cand[i];
      if (side == 0) { if (s > T) { c2++; accf += fmaxf(1.0f - s, 0.0f); } }
      else           { if (s < T) { c2++; accf += fmaxf(s, 0.0f); } }
    }
    double accd = accf;
#pragma unroll
    for (int o = 32; o > 0; o >>= 1) { accd += __shfl_xor(accd, o); c2 += __shfl_xor(c2, o); }
    if (lane == 0) { racc[wid] = accd; rcnt[wid] = c2; }
    __syncthreads();
    if (tid == 0) {
      double a = 0.0;
      unsigned int c = 0;
      for (int i = 0; i < SF_T / 64; ++i) { a += racc[i]; c += rcnt[i]; }
      if (side == 0) { m->psum += a; m->pcnt += c; }
      else           { m->nsum += a; m->ncnt += c; }
    }
    __syncthreads();
  }
  if (tid == 0)
    out[0] = (float)(m->psum / (double)m->pcnt + m->nsum / (double)m->ncnt);
}

extern "C" void kernel_launch(void* const* d_in, const int* in_sizes, int n_in,
                              void* d_out, int out_size, void* d_ws, size_t ws_size,
                              hipStream_t stream) {
  const float* x = (const float*)d_in[0];
  float* out = (float*)d_out;
  char* ws = (char*)d_ws;

  float* sim = (float*)ws;                                        // 64 MB
  unsigned short* xnb = (unsigned short*)(ws + (size_t)NN * 4);   // 4 MB
  float* pcand = (float*)(ws + (size_t)NN * 4 + (size_t)N * D * 2);          // 1 MB
  float* ncand = (float*)(ws + (size_t)NN * 4 + (size_t)N * D * 2 + CAND_CAP * 4);
  Meta* meta = (Meta*)(ws + (size_t)NN * 4 + (size_t)N * D * 2 + 2 * CAND_CAP * 4);

  const unsigned int kneg = (unsigned int)ceil((double)NN * 0.2);          // 3355444
  const unsigned int kpos = (unsigned int)ceil((double)NN * (1.0 - 0.2));  // 13421773

  hipMemsetAsync(meta, 0, sizeof(Meta), stream);
  norm_conv<<<N, 256, 0, stream>>>(x, xnb);
  dim3 ggrid(N / BM, N / BM);
  gemm_sim<<<ggrid, 256, 0, stream>>>(xnb, sim);
  hist_pass<<<1024, 256, 0, stream>>>(sim, meta);
  scan_bins<<<1, 256, 0, stream>>>(meta, kneg, kpos);
  compact_loss<<<2048, 256, 0, stream>>>(sim, meta, pcand, ncand);
  select_finalize<<<1, SF_T, 0, stream>>>(meta, pcand, ncand, out);
}